// Round 11
// baseline (358.766 us; speedup 1.0000x reference)
//
#include <hip/hip_runtime.h>
#include <math.h>
#include <float.h>
#include <stdint.h>

#define B_ 4
#define N_ 8192
#define K_ 9
#define NPTS (B_ * N_)           // 32768
#define NROWS (NPTS * K_)        // 294912
#define SPLIT 16
#define CHUNK (N_ / SPLIT)       // 512
#define NGROUP 16
#define GSIZE (CHUNK / NGROUP)   // 32
#define GSTRIDE 33               // +1 float4 pad
#define MBLK 512                 // tail blocks; (256,2) -> 2 blocks/CU co-resident
#define TTHREADS (MBLK * 256)    // 131072

// Distance: EXACT source shape of all passing rounds. Plain mul/add tree —
// identical expression tree in every kernel -> bit-identical distances
// everywhere. DO NOT rewrite with explicit fmaf / reassociation (round 5
// flipped a knife-edge 9th/10th-neighbor decision vs the reference).
__device__ __forceinline__ float dist2f(float4 q, float4 c) {
  float dot = q.x * c.x + q.y * c.y + q.z * c.z;
  return (q.w + c.w) - 2.0f * dot;
}

// ---------------- K1: two-level exact top-9 per 512-chunk (unchanged R10) ------
#define GDECL(G) float gd##G; int gi##G;
#define SCANG(G)                                                           \
  { float bgd = FLT_MAX; int bgi = 0;                                      \
    _Pragma("clang loop unroll(disable)")                                  \
    for (int jj = 0; jj < GSIZE; jj += 4) {                                \
      const float4* cp = CH + (G * GSTRIDE + jj);                          \
      float4 c0 = cp[0], c1 = cp[1], c2 = cp[2], c3 = cp[3];               \
      int j = G * GSIZE + jj;                                              \
      float d0 = dist2f(q, c0), d1 = dist2f(q, c1);                        \
      float d2 = dist2f(q, c2), d3 = dist2f(q, c3);                        \
      if (HS) {                                                            \
        d0 = (j + 0 == nl) ? FLT_MAX : d0;                                 \
        d1 = (j + 1 == nl) ? FLT_MAX : d1;                                 \
        d2 = (j + 2 == nl) ? FLT_MAX : d2;                                 \
        d3 = (j + 3 == nl) ? FLT_MAX : d3;                                 \
      }                                                                    \
      bool l0 = d0 < bgd; bgd = l0 ? d0 : bgd; bgi = l0 ? (j + 0) : bgi;   \
      bool l1 = d1 < bgd; bgd = l1 ? d1 : bgd; bgi = l1 ? (j + 1) : bgi;   \
      bool l2 = d2 < bgd; bgd = l2 ? d2 : bgd; bgi = l2 ? (j + 2) : bgi;   \
      bool l3 = d3 < bgd; bgd = l3 ? d3 : bgd; bgi = l3 ? (j + 3) : bgi;   \
    }                                                                      \
    gd##G = bgd; gi##G = bgi; }
#define LM(G)                                                              \
  { bool lt = gd##G < wd;                                                  \
    wd = lt ? gd##G : wd; wi = lt ? gi##G : wi; wg = lt ? G : wg; }
#define WBK(G)                                                             \
  { bool m = (wg == G); gd##G = m ? nd : gd##G; gi##G = m ? ni : gi##G; }

template <bool HS>
__device__ __forceinline__ void knn_chunk(const float4* CH, float4 q, int nl,
                                          int j0, int s, int p,
                                          uint2* __restrict__ PBDI) {
  GDECL(0) GDECL(1) GDECL(2) GDECL(3) GDECL(4) GDECL(5) GDECL(6) GDECL(7)
  GDECL(8) GDECL(9) GDECL(10) GDECL(11) GDECL(12) GDECL(13) GDECL(14) GDECL(15)

  SCANG(0) SCANG(1) SCANG(2) SCANG(3) SCANG(4) SCANG(5) SCANG(6) SCANG(7)
  SCANG(8) SCANG(9) SCANG(10) SCANG(11) SCANG(12) SCANG(13) SCANG(14) SCANG(15)

#pragma clang loop unroll(disable)
  for (int r = 0; r < K_; ++r) {
    float wd = gd0; int wi = gi0; int wg = 0;
    LM(1) LM(2) LM(3) LM(4) LM(5) LM(6) LM(7)
    LM(8) LM(9) LM(10) LM(11) LM(12) LM(13) LM(14) LM(15)
    uint2 o; o.x = __float_as_uint(wd); o.y = (unsigned)(j0 + wi);
    PBDI[(size_t)(s * K_ + r) * NPTS + p] = o;     // coalesced 8B

    int ab = wg * GSTRIDE;
    int jb = wg * GSIZE;
    float nd = FLT_MAX; int ni = 0;
#pragma clang loop unroll(disable)
    for (int jj = 0; jj < GSIZE; jj += 4) {
      const float4* cp = CH + (ab + jj);
      float4 c0 = cp[0], c1 = cp[1], c2 = cp[2], c3 = cp[3];
      int j = jb + jj;
      float d0 = dist2f(q, c0), d1 = dist2f(q, c1);
      float d2 = dist2f(q, c2), d3 = dist2f(q, c3);
      if (HS) {
        d0 = (j + 0 == nl) ? FLT_MAX : d0;
        d1 = (j + 1 == nl) ? FLT_MAX : d1;
        d2 = (j + 2 == nl) ? FLT_MAX : d2;
        d3 = (j + 3 == nl) ? FLT_MAX : d3;
      }
      bool k0 = (d0 > wd) | ((d0 == wd) & ((j + 0) > wi));
      bool k1 = (d1 > wd) | ((d1 == wd) & ((j + 1) > wi));
      bool k2 = (d2 > wd) | ((d2 == wd) & ((j + 2) > wi));
      bool k3 = (d3 > wd) | ((d3 == wd) & ((j + 3) > wi));
      d0 = k0 ? d0 : FLT_MAX;
      d1 = k1 ? d1 : FLT_MAX;
      d2 = k2 ? d2 : FLT_MAX;
      d3 = k3 ? d3 : FLT_MAX;
      bool l0 = d0 < nd; nd = l0 ? d0 : nd; ni = l0 ? (j + 0) : ni;
      bool l1 = d1 < nd; nd = l1 ? d1 : nd; ni = l1 ? (j + 1) : ni;
      bool l2 = d2 < nd; nd = l2 ? d2 : nd; ni = l2 ? (j + 2) : ni;
      bool l3 = d3 < nd; nd = l3 ? d3 : nd; ni = l3 ? (j + 3) : ni;
    }
    WBK(0) WBK(1) WBK(2) WBK(3) WBK(4) WBK(5) WBK(6) WBK(7)
    WBK(8) WBK(9) WBK(10) WBK(11) WBK(12) WBK(13) WBK(14) WBK(15)
  }
}

__launch_bounds__(256, 6)
__global__ void k_knn(const float* __restrict__ x, uint2* __restrict__ PBDI) {
  __shared__ float4 CH[NGROUP * GSTRIDE];   // 8448 B
  int bid = blockIdx.x;
  int pq = bid >> 4;
  int s = bid & (SPLIT - 1);
  int p = pq * 256 + threadIdx.x;
  int b = p >> 13;
  int n = p & (N_ - 1);
  int bO = b * N_;
  int j0 = s * CHUNK;

  for (int t = threadIdx.x; t < CHUNK; t += 256) {
    const float* xp = x + 3 * (size_t)(bO + j0 + t);
    float a = xp[0], bb = xp[1], cc = xp[2];
    CH[(t >> 5) * GSTRIDE + (t & 31)] = make_float4(a, bb, cc, a * a + bb * bb + cc * cc);
  }
  const float* xq = x + 3 * (size_t)p;
  float qa = xq[0], qb = xq[1], qc = xq[2];
  float4 q = make_float4(qa, qb, qc, qa * qa + qb * qb + qc * qc);
  __syncthreads();

  int n0 = (pq * 256) & (N_ - 1);
  int nl = n - j0;
  if (s == (n0 >> 9)) knn_chunk<true >(CH, q, nl, j0, s, p, PBDI);
  else                knn_chunk<false>(CH, q, nl, j0, s, p, PBDI);
}

// ---------------- K2: fused tail, 4 phases, tournament merge -------------------
// Tournament over 16 sorted lists (ascending disjoint index ranges): strict-<
// min over heads in ascending list order == exact lex (d, idx) == top_k
// tie-breaking. ~150 VALU/round vs ~800 for 16 inserts; code ~10 KB vs 58 KB
// (round 10's unrolled insertion merge blew the 32 KB L1I).
#define HDECL(L) float hd##L; int hi##L; int rk##L;
#define HINIT(L)                                                          \
  { uint2 v = PBDI[(size_t)(L * K_) * NPTS + p];                          \
    hd##L = __uint_as_float(v.x); hi##L = (int)v.y; rk##L = 1; }
#define LMH(L)                                                            \
  { bool lt = hd##L < wd; wd = lt ? hd##L : wd; wi = lt ? hi##L : wi;     \
    wg = lt ? L : wg; }
#define RSEL(L) rr = (wg == L) ? rk##L : rr;
#define HADV(L)                                                           \
  { bool m = (wg == L); hd##L = m ? nhd : hd##L; hi##L = m ? nhi : hi##L; \
    rk##L = m ? (rk##L + 1) : rk##L; }
#define TROUND(r, DO_ADV)                                                 \
  { float wd = hd0; int wi = hi0; int wg = 0;                             \
    LMH(1) LMH(2) LMH(3) LMH(4) LMH(5) LMH(6) LMH(7)                      \
    LMH(8) LMH(9) LMH(10) LMH(11) LMH(12) LMH(13) LMH(14) LMH(15)         \
    oi##r = wi;                                                           \
    if (DO_ADV) {                                                         \
      int rr = rk0;                                                       \
      RSEL(1) RSEL(2) RSEL(3) RSEL(4) RSEL(5) RSEL(6) RSEL(7)             \
      RSEL(8) RSEL(9) RSEL(10) RSEL(11) RSEL(12) RSEL(13) RSEL(14) RSEL(15)\
      int rc = rr > 8 ? 8 : rr;                                           \
      uint2 v = PBDI[(size_t)(wg * K_ + rc) * NPTS + p];                  \
      float nhd = (rr > 8) ? FLT_MAX : __uint_as_float(v.x);              \
      int nhi = (int)v.y;                                                 \
      HADV(0) HADV(1) HADV(2) HADV(3) HADV(4) HADV(5) HADV(6) HADV(7)     \
      HADV(8) HADV(9) HADV(10) HADV(11) HADV(12) HADV(13) HADV(14) HADV(15)\
    } }

#define MKREL(T)                                                          \
  float rx##T, ry##T, rz##T, ph##T;                                       \
  { const float* mp = x + 3 * (size_t)(bO + oi##T);                       \
    rx##T = mp[0] - qa; ry##T = mp[1] - qb; rz##T = mp[2] - qc;           \
    ph##T = atan2f(ry##T, rx##T); }

#define CE(A, Bv)                                                         \
  { bool lt = ph##Bv < ph##A; float t0;                                   \
    t0 = ph##A; ph##A = lt ? ph##Bv : t0; ph##Bv = lt ? t0 : ph##Bv;      \
    t0 = rx##A; rx##A = lt ? rx##Bv : t0; rx##Bv = lt ? t0 : rx##Bv;      \
    t0 = ry##A; ry##A = lt ? ry##Bv : t0; ry##Bv = lt ? t0 : ry##Bv;      \
    t0 = rz##A; rz##A = lt ? rz##Bv : t0; rz##Bv = lt ? t0 : rz##Bv; }

#define STREL(T)                                                          \
  { REL[(size_t)(0 * K_ + T) * NPTS + p] = rx##T;                         \
    REL[(size_t)(1 * K_ + T) * NPTS + p] = ry##T;                         \
    REL[(size_t)(2 * K_ + T) * NPTS + p] = rz##T; }

// Device-scope spin barrier; MBLK blocks all co-resident by (256,2) resources.
__device__ __forceinline__ void gridbar(int* ctr, int target) {
  __syncthreads();
  if (threadIdx.x == 0) {
    __hip_atomic_fetch_add(ctr, 1, __ATOMIC_RELEASE, __HIP_MEMORY_SCOPE_AGENT);
    while (__hip_atomic_load(ctr, __ATOMIC_ACQUIRE, __HIP_MEMORY_SCOPE_AGENT) < target) {
      __builtin_amdgcn_s_sleep(8);
    }
  }
  __syncthreads();
}

__launch_bounds__(256, 2)
__global__ void k_tail(const float* __restrict__ x, const uint2* __restrict__ PBDI,
                       const float* __restrict__ W1, const float* __restrict__ b1,
                       const float* __restrict__ g1, const float* __restrict__ be1,
                       const float* __restrict__ W2, const float* __restrict__ b2,
                       const float* __restrict__ g2, const float* __restrict__ be2,
                       float* __restrict__ REL, float* __restrict__ SGN,
                       float* __restrict__ H1, float* __restrict__ H2,
                       double* __restrict__ ACC, int* __restrict__ CTR,
                       float* __restrict__ out) {
  double* ACC1 = ACC;
  double* ACC2 = ACC + 20;
  __shared__ double sred[4][20];
  __shared__ float MR[20];
  int lane = threadIdx.x & 63, wv = threadIdx.x >> 6;
  int gtid = blockIdx.x * 256 + threadIdx.x;

  // ---- phase 1 (per-point; 64 active threads/block): tournament merge,
  //      phi-sort, sign -> REL, SGN ----
  if (threadIdx.x < 64) {
    int p = blockIdx.x * 64 + threadIdx.x;   // MBLK*64 == NPTS
    int b = p >> 13;
    int bO = b * N_;
    const float* xq = x + 3 * (size_t)p;
    float qa = xq[0], qb = xq[1], qc = xq[2];

    HDECL(0) HDECL(1) HDECL(2) HDECL(3) HDECL(4) HDECL(5) HDECL(6) HDECL(7)
    HDECL(8) HDECL(9) HDECL(10) HDECL(11) HDECL(12) HDECL(13) HDECL(14) HDECL(15)
    HINIT(0) HINIT(1) HINIT(2) HINIT(3) HINIT(4) HINIT(5) HINIT(6) HINIT(7)
    HINIT(8) HINIT(9) HINIT(10) HINIT(11) HINIT(12) HINIT(13) HINIT(14) HINIT(15)

    int oi0, oi1, oi2, oi3, oi4, oi5, oi6, oi7, oi8;
    TROUND(0, true) TROUND(1, true) TROUND(2, true) TROUND(3, true)
    TROUND(4, true) TROUND(5, true) TROUND(6, true) TROUND(7, true)
    TROUND(8, false)

    MKREL(0) MKREL(1) MKREL(2) MKREL(3) MKREL(4)
    MKREL(5) MKREL(6) MKREL(7) MKREL(8)

    // stable insertion-sort network ascending by phi (36 strict-< CEs)
    CE(0,1)
    CE(1,2) CE(0,1)
    CE(2,3) CE(1,2) CE(0,1)
    CE(3,4) CE(2,3) CE(1,2) CE(0,1)
    CE(4,5) CE(3,4) CE(2,3) CE(1,2) CE(0,1)
    CE(5,6) CE(4,5) CE(3,4) CE(2,3) CE(1,2) CE(0,1)
    CE(6,7) CE(5,6) CE(4,5) CE(3,4) CE(2,3) CE(1,2) CE(0,1)
    CE(7,8) CE(6,7) CE(5,6) CE(4,5) CE(3,4) CE(2,3) CE(1,2) CE(0,1)

    // sign from triangle 0's NORMALIZED nx (reference semantics)
    float nx0 = ry0 * rz1 - rz0 * ry1;
    float ny0 = rz0 * rx1 - rx0 * rz1;
    float nz0 = rx0 * ry1 - ry0 * rx1;
    float nrm0 = sqrtf(nx0 * nx0 + ny0 * ny0 + nz0 * nz0) + 1e-6f;
    SGN[p] = ((nx0 / nrm0) > 0.0f) ? 1.0f : -1.0f;

    STREL(0) STREL(1) STREL(2) STREL(3) STREL(4)
    STREL(5) STREL(6) STREL(7) STREL(8)
  }

  gridbar(CTR, MBLK);

  // ---- phase 2 (per-row): features + @W1+b1 -> H1 + stats1 ----
  {
    double sum[10], ss[10];
#pragma unroll
    for (int c = 0; c < 10; ++c) { sum[c] = 0.0; ss[c] = 0.0; }

#pragma clang loop unroll(disable)
    for (int r = gtid; r < NROWS; r += TTHREADS) {
      int t = r >> 15;
      int p = r & (NPTS - 1);
      int t2 = (t + 1 == K_) ? 0 : t + 1;
      float v1x = REL[(size_t)(0 * K_ + t) * NPTS + p];
      float v1y = REL[(size_t)(1 * K_ + t) * NPTS + p];
      float v1z = REL[(size_t)(2 * K_ + t) * NPTS + p];
      float v2x = REL[(size_t)(0 * K_ + t2) * NPTS + p];
      float v2y = REL[(size_t)(1 * K_ + t2) * NPTS + p];
      float v2z = REL[(size_t)(2 * K_ + t2) * NPTS + p];
      float sgn = SGN[p];

      float cx = 0.5f * (v1x + v2x);
      float cy = 0.5f * (v1y + v2y);
      float cz = 0.5f * (v1z + v2z);
      float nx = v1y * v2z - v1z * v2y;
      float ny = v1z * v2x - v1x * v2z;
      float nz = v1x * v2y - v1y * v2x;
      float nrm = sqrtf(nx * nx + ny * ny + nz * nz) + 1e-6f;
      nx /= nrm; ny /= nrm; nz /= nrm;
      nx *= sgn; ny *= sgn; nz *= sgn;
      float pos = (nx * cx + ny * cy + nz * cz) / 1.7320508075688772f;

      float fv[7] = {cx, cy, cz, nx, ny, nz, pos};
#pragma unroll
      for (int c = 0; c < 10; ++c) {
        float h = b1[c];
#pragma unroll
        for (int rr = 0; rr < 7; ++rr) h = fmaf(fv[rr], W1[rr * 10 + c], h);
        H1[(size_t)c * NROWS + r] = h;
        double hd = (double)h;
        sum[c] += hd; ss[c] += hd * hd;
      }
    }

#pragma unroll
    for (int c = 0; c < 10; ++c) {
      double a = sum[c];
#pragma unroll
      for (int off = 32; off > 0; off >>= 1) a += __shfl_down(a, off);
      if (lane == 0) sred[wv][c] = a;
      double qq = ss[c];
#pragma unroll
      for (int off = 32; off > 0; off >>= 1) qq += __shfl_down(qq, off);
      if (lane == 0) sred[wv][10 + c] = qq;
    }
    __syncthreads();
    if (threadIdx.x < 20) {
      atomicAdd(&ACC1[threadIdx.x],
                sred[0][threadIdx.x] + sred[1][threadIdx.x] +
                sred[2][threadIdx.x] + sred[3][threadIdx.x]);
    }
  }

  gridbar(CTR, 2 * MBLK);

  // ---- phase 3 (per-row): bn1 + relu + @W2+b2 -> H2 + stats2 ----
  {
    if (threadIdx.x < 10) {
      double mu = ACC1[threadIdx.x] / (double)NROWS;
      double var = ACC1[10 + threadIdx.x] / (double)NROWS - mu * mu;
      MR[threadIdx.x] = (float)mu;
      MR[10 + threadIdx.x] = (float)(1.0 / sqrt(var + 1e-5));
    }
    __syncthreads();

    double sum[10], ss[10];
#pragma unroll
    for (int c = 0; c < 10; ++c) { sum[c] = 0.0; ss[c] = 0.0; }

#pragma clang loop unroll(disable)
    for (int r = gtid; r < NROWS; r += TTHREADS) {
      float v[10];
#pragma unroll
      for (int c = 0; c < 10; ++c) {
        float h = H1[(size_t)c * NROWS + r];
        float z = g1[c] * (h - MR[c]) * MR[10 + c] + be1[c];
        v[c] = z > 0.0f ? z : 0.0f;
      }
#pragma unroll
      for (int c = 0; c < 10; ++c) {
        float h = b2[c];
#pragma unroll
        for (int t = 0; t < 10; ++t) h = fmaf(v[t], W2[t * 10 + c], h);
        H2[(size_t)c * NROWS + r] = h;
        double hd = (double)h;
        sum[c] += hd; ss[c] += hd * hd;
      }
    }

    __syncthreads();   // sred reuse
#pragma unroll
    for (int c = 0; c < 10; ++c) {
      double a = sum[c];
#pragma unroll
      for (int off = 32; off > 0; off >>= 1) a += __shfl_down(a, off);
      if (lane == 0) sred[wv][c] = a;
      double qq = ss[c];
#pragma unroll
      for (int off = 32; off > 0; off >>= 1) qq += __shfl_down(qq, off);
      if (lane == 0) sred[wv][10 + c] = qq;
    }
    __syncthreads();
    if (threadIdx.x < 20) {
      atomicAdd(&ACC2[threadIdx.x],
                sred[0][threadIdx.x] + sred[1][threadIdx.x] +
                sred[2][threadIdx.x] + sred[3][threadIdx.x]);
    }
  }

  gridbar(CTR, 3 * MBLK);

  // ---- phase 4 (per-point): bn2 + relu + max over k -> out ----
  {
    if (threadIdx.x < 10) {
      double mu = ACC2[threadIdx.x] / (double)NROWS;
      double var = ACC2[10 + threadIdx.x] / (double)NROWS - mu * mu;
      MR[threadIdx.x] = (float)mu;
      MR[10 + threadIdx.x] = (float)(1.0 / sqrt(var + 1e-5));
    }
    __syncthreads();

    if (gtid < NPTS) {
      int p = gtid;
#pragma unroll
      for (int c = 0; c < 10; ++c) {
        float m = -FLT_MAX;
#pragma unroll
        for (int j = 0; j < K_; ++j) {
          float h = H2[(size_t)c * NROWS + j * NPTS + p];   // coalesced
          float z = g2[c] * (h - MR[c]) * MR[10 + c] + be2[c];
          z = z > 0.0f ? z : 0.0f;
          m = fmaxf(m, z);
        }
        out[(size_t)p * 10 + c] = m;
      }
    }
  }
}

extern "C" void kernel_launch(void* const* d_in, const int* in_sizes, int n_in,
                              void* d_out, int out_size, void* d_ws, size_t ws_size,
                              hipStream_t stream) {
  (void)in_sizes; (void)n_in; (void)out_size; (void)ws_size;
  const float* x  = (const float*)d_in[0];
  const float* W1 = (const float*)d_in[1];
  const float* b1 = (const float*)d_in[2];
  const float* g1 = (const float*)d_in[3];
  const float* be1= (const float*)d_in[4];
  const float* W2 = (const float*)d_in[5];
  const float* b2 = (const float*)d_in[6];
  const float* g2 = (const float*)d_in[7];
  const float* be2= (const float*)d_in[8];
  float* out = (float*)d_out;

  char* base = (char*)d_ws;
  uint2*  PBDI = (uint2*)base;                          // 144 slices × 256KB = 37.7MB
  // H1 aliases PBDI slices [0,48), H2 slices [48,96): PBDI fully consumed by
  // tail phase 1 before the barrier; H1 written in phase 2.
  float*  H1 = (float*)base;
  float*  H2 = (float*)(base + (size_t)48 * NPTS * 8);
  char*   tailmem = base + (size_t)SPLIT * K_ * NPTS * 8;
  float*  REL = (float*)tailmem;                        // 27 slices, 3.54MB
  float*  SGN = REL + (size_t)3 * K_ * NPTS;            // 128KB
  char*   sync = (char*)(SGN + NPTS);
  double* ACC = (double*)sync;                          // 40 doubles
  int*    CTR = (int*)(sync + 40 * sizeof(double));

  hipMemsetAsync(sync, 0, 40 * sizeof(double) + sizeof(int), stream);
  k_knn<<<(NPTS / 256) * SPLIT, 256, 0, stream>>>(x, PBDI);
  k_tail<<<MBLK, 256, 0, stream>>>(x, PBDI, W1, b1, g1, be1, W2, b2, g2, be2,
                                   REL, SGN, H1, H2, ACC, CTR, out);
}

// Round 12
// 274.912 us; speedup vs baseline: 1.3050x; 1.3050x over previous
//
#include <hip/hip_runtime.h>
#include <math.h>
#include <float.h>
#include <stdint.h>

#define B_ 4
#define N_ 8192
#define K_ 9
#define NPTS (B_ * N_)           // 32768
#define NROWS (NPTS * K_)        // 294912
#define SPLIT 16
#define CHUNK (N_ / SPLIT)       // 512
#define NGROUP 16
#define GSIZE (CHUNK / NGROUP)   // 32
#define GSTRIDE 33               // +1 float4 pad

// Distance: EXACT source shape of all passing rounds. Plain mul/add tree —
// identical expression tree in every kernel -> bit-identical distances
// everywhere. DO NOT rewrite with explicit fmaf / reassociation (round 5
// flipped a knife-edge 9th/10th-neighbor decision vs the reference).
__device__ __forceinline__ float dist2f(float4 q, float4 c) {
  float dot = q.x * c.x + q.y * c.y + q.z * c.z;
  return (q.w + c.w) - 2.0f * dot;
}

// ---------------- K1: two-level exact top-9 per 512-chunk (unchanged R10) ------
#define GDECL(G) float gd##G; int gi##G;
#define SCANG(G)                                                           \
  { float bgd = FLT_MAX; int bgi = 0;                                      \
    _Pragma("clang loop unroll(disable)")                                  \
    for (int jj = 0; jj < GSIZE; jj += 4) {                                \
      const float4* cp = CH + (G * GSTRIDE + jj);                          \
      float4 c0 = cp[0], c1 = cp[1], c2 = cp[2], c3 = cp[3];               \
      int j = G * GSIZE + jj;                                              \
      float d0 = dist2f(q, c0), d1 = dist2f(q, c1);                        \
      float d2 = dist2f(q, c2), d3 = dist2f(q, c3);                        \
      if (HS) {                                                            \
        d0 = (j + 0 == nl) ? FLT_MAX : d0;                                 \
        d1 = (j + 1 == nl) ? FLT_MAX : d1;                                 \
        d2 = (j + 2 == nl) ? FLT_MAX : d2;                                 \
        d3 = (j + 3 == nl) ? FLT_MAX : d3;                                 \
      }                                                                    \
      bool l0 = d0 < bgd; bgd = l0 ? d0 : bgd; bgi = l0 ? (j + 0) : bgi;   \
      bool l1 = d1 < bgd; bgd = l1 ? d1 : bgd; bgi = l1 ? (j + 1) : bgi;   \
      bool l2 = d2 < bgd; bgd = l2 ? d2 : bgd; bgi = l2 ? (j + 2) : bgi;   \
      bool l3 = d3 < bgd; bgd = l3 ? d3 : bgd; bgi = l3 ? (j + 3) : bgi;   \
    }                                                                      \
    gd##G = bgd; gi##G = bgi; }
#define LM(G)                                                              \
  { bool lt = gd##G < wd;                                                  \
    wd = lt ? gd##G : wd; wi = lt ? gi##G : wi; wg = lt ? G : wg; }
#define WBK(G)                                                             \
  { bool m = (wg == G); gd##G = m ? nd : gd##G; gi##G = m ? ni : gi##G; }

template <bool HS>
__device__ __forceinline__ void knn_chunk(const float4* CH, float4 q, int nl,
                                          int j0, int s, int p,
                                          uint2* __restrict__ PBDI) {
  GDECL(0) GDECL(1) GDECL(2) GDECL(3) GDECL(4) GDECL(5) GDECL(6) GDECL(7)
  GDECL(8) GDECL(9) GDECL(10) GDECL(11) GDECL(12) GDECL(13) GDECL(14) GDECL(15)

  SCANG(0) SCANG(1) SCANG(2) SCANG(3) SCANG(4) SCANG(5) SCANG(6) SCANG(7)
  SCANG(8) SCANG(9) SCANG(10) SCANG(11) SCANG(12) SCANG(13) SCANG(14) SCANG(15)

#pragma clang loop unroll(disable)
  for (int r = 0; r < K_; ++r) {
    float wd = gd0; int wi = gi0; int wg = 0;
    LM(1) LM(2) LM(3) LM(4) LM(5) LM(6) LM(7)
    LM(8) LM(9) LM(10) LM(11) LM(12) LM(13) LM(14) LM(15)
    uint2 o; o.x = __float_as_uint(wd); o.y = (unsigned)(j0 + wi);
    PBDI[(size_t)(s * K_ + r) * NPTS + p] = o;     // coalesced 8B

    int ab = wg * GSTRIDE;
    int jb = wg * GSIZE;
    float nd = FLT_MAX; int ni = 0;
#pragma clang loop unroll(disable)
    for (int jj = 0; jj < GSIZE; jj += 4) {
      const float4* cp = CH + (ab + jj);
      float4 c0 = cp[0], c1 = cp[1], c2 = cp[2], c3 = cp[3];
      int j = jb + jj;
      float d0 = dist2f(q, c0), d1 = dist2f(q, c1);
      float d2 = dist2f(q, c2), d3 = dist2f(q, c3);
      if (HS) {
        d0 = (j + 0 == nl) ? FLT_MAX : d0;
        d1 = (j + 1 == nl) ? FLT_MAX : d1;
        d2 = (j + 2 == nl) ? FLT_MAX : d2;
        d3 = (j + 3 == nl) ? FLT_MAX : d3;
      }
      bool k0 = (d0 > wd) | ((d0 == wd) & ((j + 0) > wi));
      bool k1 = (d1 > wd) | ((d1 == wd) & ((j + 1) > wi));
      bool k2 = (d2 > wd) | ((d2 == wd) & ((j + 2) > wi));
      bool k3 = (d3 > wd) | ((d3 == wd) & ((j + 3) > wi));
      d0 = k0 ? d0 : FLT_MAX;
      d1 = k1 ? d1 : FLT_MAX;
      d2 = k2 ? d2 : FLT_MAX;
      d3 = k3 ? d3 : FLT_MAX;
      bool l0 = d0 < nd; nd = l0 ? d0 : nd; ni = l0 ? (j + 0) : ni;
      bool l1 = d1 < nd; nd = l1 ? d1 : nd; ni = l1 ? (j + 1) : ni;
      bool l2 = d2 < nd; nd = l2 ? d2 : nd; ni = l2 ? (j + 2) : ni;
      bool l3 = d3 < nd; nd = l3 ? d3 : nd; ni = l3 ? (j + 3) : ni;
    }
    WBK(0) WBK(1) WBK(2) WBK(3) WBK(4) WBK(5) WBK(6) WBK(7)
    WBK(8) WBK(9) WBK(10) WBK(11) WBK(12) WBK(13) WBK(14) WBK(15)
  }
}

__launch_bounds__(256, 6)
__global__ void k_knn(const float* __restrict__ x, uint2* __restrict__ PBDI) {
  __shared__ float4 CH[NGROUP * GSTRIDE];   // 8448 B
  int bid = blockIdx.x;
  int pq = bid >> 4;
  int s = bid & (SPLIT - 1);
  int p = pq * 256 + threadIdx.x;
  int b = p >> 13;
  int n = p & (N_ - 1);
  int bO = b * N_;
  int j0 = s * CHUNK;

  for (int t = threadIdx.x; t < CHUNK; t += 256) {
    const float* xp = x + 3 * (size_t)(bO + j0 + t);
    float a = xp[0], bb = xp[1], cc = xp[2];
    CH[(t >> 5) * GSTRIDE + (t & 31)] = make_float4(a, bb, cc, a * a + bb * bb + cc * cc);
  }
  const float* xq = x + 3 * (size_t)p;
  float qa = xq[0], qb = xq[1], qc = xq[2];
  float4 q = make_float4(qa, qb, qc, qa * qa + qb * qb + qc * qc);
  __syncthreads();

  int n0 = (pq * 256) & (N_ - 1);
  int nl = n - j0;
  if (s == (n0 >> 9)) knn_chunk<true >(CH, q, nl, j0, s, p, PBDI);
  else                knn_chunk<false>(CH, q, nl, j0, s, p, PBDI);
}

// ---------------- K2: merge + phi-sort + features + W1 -> H1 + stats1 ----------
// 512 blocks x 256 threads = 4 threads/point. Wave q sub-merges lists
// s in [4q, 4q+4) (ascending (s,rank) -> exact tie-breaking); wave 0 does the
// final 4-way merge (ascending q = ascending s) + sort; rows fan out to all
// 256 threads. No grid barriers — launch boundaries provide global sync.
#define LVL(bdv, biv)                                                     \
  { bool lt = cd < (bdv); float td = (bdv); int ti = (biv);               \
    (bdv) = lt ? cd : (bdv); (biv) = lt ? ci : (biv);                     \
    cd = lt ? td : cd; ci = lt ? ti : ci; }
#define INS9ALL()                                                         \
  LVL(b0d, b0i) LVL(b1d, b1i) LVL(b2d, b2i) LVL(b3d, b3i) LVL(b4d, b4i)  \
  LVL(b5d, b5i) LVL(b6d, b6i) LVL(b7d, b7i) LVL(b8d, b8i)
#define TOP9_DECL()                                                       \
  float b0d = FLT_MAX, b1d = FLT_MAX, b2d = FLT_MAX, b3d = FLT_MAX,       \
        b4d = FLT_MAX, b5d = FLT_MAX, b6d = FLT_MAX, b7d = FLT_MAX,       \
        b8d = FLT_MAX;                                                    \
  int b0i = 0, b1i = 0, b2i = 0, b3i = 0, b4i = 0, b5i = 0, b6i = 0,      \
      b7i = 0, b8i = 0;

#define MKREL(T)                                                          \
  float rx##T, ry##T, rz##T, ph##T;                                       \
  { const float* mp = x + 3 * (size_t)(bO + b##T##i);                     \
    rx##T = mp[0] - qa; ry##T = mp[1] - qb; rz##T = mp[2] - qc;           \
    ph##T = atan2f(ry##T, rx##T); }

#define CE(A, Bv)                                                         \
  { bool lt = ph##Bv < ph##A; float t0;                                   \
    t0 = ph##A; ph##A = lt ? ph##Bv : t0; ph##Bv = lt ? t0 : ph##Bv;      \
    t0 = rx##A; rx##A = lt ? rx##Bv : t0; rx##Bv = lt ? t0 : rx##Bv;      \
    t0 = ry##A; ry##A = lt ? ry##Bv : t0; ry##Bv = lt ? t0 : ry##Bv;      \
    t0 = rz##A; rz##A = lt ? rz##Bv : t0; rz##Bv = lt ? t0 : rz##Bv; }

#define ST9(arr, v0, v1, v2, v3, v4, v5, v6, v7, v8)                      \
  arr[0 * 64 + pl] = v0; arr[1 * 64 + pl] = v1; arr[2 * 64 + pl] = v2;    \
  arr[3 * 64 + pl] = v3; arr[4 * 64 + pl] = v4; arr[5 * 64 + pl] = v5;    \
  arr[6 * 64 + pl] = v6; arr[7 * 64 + pl] = v7; arr[8 * 64 + pl] = v8;

__launch_bounds__(256, 4)
__global__ void k_tail1(const float* __restrict__ x, const uint2* __restrict__ PBDI,
                        const float* __restrict__ W1, const float* __restrict__ b1,
                        float* __restrict__ H1, double* __restrict__ ACC1) {
  __shared__ float  LMD[64 * 37];        // [pl*37 + q*9 + r], pad -> odd dword stride
  __shared__ int    LMI[64 * 37];
  __shared__ float  LREL[3][9 * 64];     // [comp][t*64 + pl]
  __shared__ float  LSGN[64];
  __shared__ double sred[4][20];

  int q = threadIdx.x >> 6;              // wave id 0..3
  int pl = threadIdx.x & 63;
  int pbase = blockIdx.x * 64;
  int p = pbase + pl;

  // ---- sub-merge: wave q merges lists s in [4q, 4q+4) (36 coalesced entries)
  {
    TOP9_DECL();
#pragma clang loop unroll_count(4)
    for (int e = 0; e < 4 * K_; ++e) {
      uint2 v = PBDI[(size_t)(q * 4 * K_ + e) * NPTS + p];
      float cd = __uint_as_float(v.x);
      int ci = (int)v.y;
      INS9ALL();
    }
    int base = pl * 37 + q * 9;
    LMD[base + 0] = b0d; LMD[base + 1] = b1d; LMD[base + 2] = b2d;
    LMD[base + 3] = b3d; LMD[base + 4] = b4d; LMD[base + 5] = b5d;
    LMD[base + 6] = b6d; LMD[base + 7] = b7d; LMD[base + 8] = b8d;
    LMI[base + 0] = b0i; LMI[base + 1] = b1i; LMI[base + 2] = b2i;
    LMI[base + 3] = b3i; LMI[base + 4] = b4i; LMI[base + 5] = b5i;
    LMI[base + 6] = b6i; LMI[base + 7] = b7i; LMI[base + 8] = b8i;
  }
  __syncthreads();

  // ---- final merge + REL + phi-sort + sign (wave 0, one lane per point) ----
  if (q == 0) {
    int b = p >> 13;
    int bO = b * N_;
    const float* xq = x + 3 * (size_t)p;
    float qa = xq[0], qb = xq[1], qc = xq[2];

    TOP9_DECL();
#pragma clang loop unroll_count(3)
    for (int e = 0; e < 4 * K_; ++e) {   // ascending q (=s) then rank
      float cd = LMD[pl * 37 + e];
      int ci = LMI[pl * 37 + e];
      INS9ALL();
    }

    MKREL(0) MKREL(1) MKREL(2) MKREL(3) MKREL(4)
    MKREL(5) MKREL(6) MKREL(7) MKREL(8)

    // stable insertion-sort network ascending by phi (36 strict-< CEs)
    CE(0,1)
    CE(1,2) CE(0,1)
    CE(2,3) CE(1,2) CE(0,1)
    CE(3,4) CE(2,3) CE(1,2) CE(0,1)
    CE(4,5) CE(3,4) CE(2,3) CE(1,2) CE(0,1)
    CE(5,6) CE(4,5) CE(3,4) CE(2,3) CE(1,2) CE(0,1)
    CE(6,7) CE(5,6) CE(4,5) CE(3,4) CE(2,3) CE(1,2) CE(0,1)
    CE(7,8) CE(6,7) CE(5,6) CE(4,5) CE(3,4) CE(2,3) CE(1,2) CE(0,1)

    // sign from triangle 0's NORMALIZED nx (reference semantics)
    float nx0 = ry0 * rz1 - rz0 * ry1;
    float ny0 = rz0 * rx1 - rx0 * rz1;
    float nz0 = rx0 * ry1 - ry0 * rx1;
    float nrm0 = sqrtf(nx0 * nx0 + ny0 * ny0 + nz0 * nz0) + 1e-6f;
    LSGN[pl] = ((nx0 / nrm0) > 0.0f) ? 1.0f : -1.0f;

    ST9(LREL[0], rx0, rx1, rx2, rx3, rx4, rx5, rx6, rx7, rx8)
    ST9(LREL[1], ry0, ry1, ry2, ry3, ry4, ry5, ry6, ry7, ry8)
    ST9(LREL[2], rz0, rz1, rz2, rz3, rz4, rz5, rz6, rz7, rz8)
  }
  __syncthreads();

  // ---- rows: 576 rows / 256 threads; feat + W1 -> H1 + fp64 stats ----
  double sum[10], ss[10];
#pragma unroll
  for (int c = 0; c < 10; ++c) { sum[c] = 0.0; ss[c] = 0.0; }

#pragma clang loop unroll(disable)
  for (int rl = threadIdx.x; rl < 9 * 64; rl += 256) {
    int t = rl >> 6;
    int pp = rl & 63;
    int t2 = (t + 1 == K_) ? 0 : t + 1;
    float v1x = LREL[0][t * 64 + pp];
    float v1y = LREL[1][t * 64 + pp];
    float v1z = LREL[2][t * 64 + pp];
    float v2x = LREL[0][t2 * 64 + pp];
    float v2y = LREL[1][t2 * 64 + pp];
    float v2z = LREL[2][t2 * 64 + pp];
    float sgn = LSGN[pp];

    float cx = 0.5f * (v1x + v2x);
    float cy = 0.5f * (v1y + v2y);
    float cz = 0.5f * (v1z + v2z);
    float nx = v1y * v2z - v1z * v2y;
    float ny = v1z * v2x - v1x * v2z;
    float nz = v1x * v2y - v1y * v2x;
    float nrm = sqrtf(nx * nx + ny * ny + nz * nz) + 1e-6f;
    nx /= nrm; ny /= nrm; nz /= nrm;
    nx *= sgn; ny *= sgn; nz *= sgn;
    float pos = (nx * cx + ny * cy + nz * cz) / 1.7320508075688772f;

    float fv[7] = {cx, cy, cz, nx, ny, nz, pos};
#pragma unroll
    for (int c = 0; c < 10; ++c) {
      float h = b1[c];
#pragma unroll
      for (int rr = 0; rr < 7; ++rr) h = fmaf(fv[rr], W1[rr * 10 + c], h);
      H1[(size_t)c * NROWS + (size_t)t * NPTS + pbase + pp] = h;  // coalesced
      double hd = (double)h;
      sum[c] += hd; ss[c] += hd * hd;
    }
  }

  int lane = threadIdx.x & 63, wv = threadIdx.x >> 6;
#pragma unroll
  for (int c = 0; c < 10; ++c) {
    double a = sum[c];
#pragma unroll
    for (int off = 32; off > 0; off >>= 1) a += __shfl_down(a, off);
    if (lane == 0) sred[wv][c] = a;
    double qq = ss[c];
#pragma unroll
    for (int off = 32; off > 0; off >>= 1) qq += __shfl_down(qq, off);
    if (lane == 0) sred[wv][10 + c] = qq;
  }
  __syncthreads();
  if (threadIdx.x < 20) {
    atomicAdd(&ACC1[threadIdx.x],
              sred[0][threadIdx.x] + sred[1][threadIdx.x] +
              sred[2][threadIdx.x] + sred[3][threadIdx.x]);
  }
}

// ---------------- K3: bn1(from ACC1) + relu + @W2+b2 -> H2 + stats2 ------------
__launch_bounds__(256)
__global__ void k_mlp2(const float* __restrict__ H1, const double* __restrict__ ACC1,
                       const float* __restrict__ g1, const float* __restrict__ be1,
                       const float* __restrict__ W2, const float* __restrict__ b2,
                       float* __restrict__ H2, double* __restrict__ ACC2) {
  __shared__ float MR[20];
  if (threadIdx.x < 10) {
    double mu = ACC1[threadIdx.x] / (double)NROWS;
    double var = ACC1[10 + threadIdx.x] / (double)NROWS - mu * mu;
    MR[threadIdx.x] = (float)mu;
    MR[10 + threadIdx.x] = (float)(1.0 / sqrt(var + 1e-5));
  }
  __syncthreads();

  int r = blockIdx.x * 256 + threadIdx.x;
  float v[10];
#pragma unroll
  for (int c = 0; c < 10; ++c) {
    float h = H1[(size_t)c * NROWS + r];
    float z = g1[c] * (h - MR[c]) * MR[10 + c] + be1[c];
    v[c] = z > 0.0f ? z : 0.0f;
  }
  float o[10];
#pragma unroll
  for (int c = 0; c < 10; ++c) {
    float h = b2[c];
#pragma unroll
    for (int t = 0; t < 10; ++t) h = fmaf(v[t], W2[t * 10 + c], h);
    o[c] = h;
    H2[(size_t)c * NROWS + r] = h;
  }

  __shared__ double sred[4][20];
  int lane = threadIdx.x & 63, wv = threadIdx.x >> 6;
#pragma unroll
  for (int c = 0; c < 10; ++c) {
    double a = (double)o[c];
#pragma unroll
    for (int off = 32; off > 0; off >>= 1) a += __shfl_down(a, off);
    if (lane == 0) sred[wv][c] = a;
    double qq = (double)o[c] * (double)o[c];
#pragma unroll
    for (int off = 32; off > 0; off >>= 1) qq += __shfl_down(qq, off);
    if (lane == 0) sred[wv][10 + c] = qq;
  }
  __syncthreads();
  if (threadIdx.x < 20) {
    atomicAdd(&ACC2[threadIdx.x],
              sred[0][threadIdx.x] + sred[1][threadIdx.x] +
              sred[2][threadIdx.x] + sred[3][threadIdx.x]);
  }
}

// ---------------- K4: bn2(from ACC2) + relu + max over k -> out -----------------
__launch_bounds__(256)
__global__ void k_out(const float* __restrict__ H2, const double* __restrict__ ACC2,
                      const float* __restrict__ g2, const float* __restrict__ be2,
                      float* __restrict__ out) {
  __shared__ float MR[20];
  if (threadIdx.x < 10) {
    double mu = ACC2[threadIdx.x] / (double)NROWS;
    double var = ACC2[10 + threadIdx.x] / (double)NROWS - mu * mu;
    MR[threadIdx.x] = (float)mu;
    MR[10 + threadIdx.x] = (float)(1.0 / sqrt(var + 1e-5));
  }
  __syncthreads();

  int p = blockIdx.x * 256 + threadIdx.x;
#pragma unroll
  for (int c = 0; c < 10; ++c) {
    float m = -FLT_MAX;
#pragma unroll
    for (int j = 0; j < K_; ++j) {
      float h = H2[(size_t)c * NROWS + j * NPTS + p];   // coalesced
      float z = g2[c] * (h - MR[c]) * MR[10 + c] + be2[c];
      z = z > 0.0f ? z : 0.0f;
      m = fmaxf(m, z);
    }
    out[(size_t)p * 10 + c] = m;
  }
}

extern "C" void kernel_launch(void* const* d_in, const int* in_sizes, int n_in,
                              void* d_out, int out_size, void* d_ws, size_t ws_size,
                              hipStream_t stream) {
  (void)in_sizes; (void)n_in; (void)out_size; (void)ws_size;
  const float* x  = (const float*)d_in[0];
  const float* W1 = (const float*)d_in[1];
  const float* b1 = (const float*)d_in[2];
  const float* g1 = (const float*)d_in[3];
  const float* be1= (const float*)d_in[4];
  const float* W2 = (const float*)d_in[5];
  const float* b2 = (const float*)d_in[6];
  const float* g2 = (const float*)d_in[7];
  const float* be2= (const float*)d_in[8];
  float* out = (float*)d_out;

  char* base = (char*)d_ws;
  uint2*  PBDI = (uint2*)base;                          // 144 slices, 37.7 MB
  float*  H1 = (float*)(base + (size_t)SPLIT * K_ * NPTS * 8);  // 11.8 MB
  double* ACC = (double*)(H1 + (size_t)10 * NROWS);     // 40 doubles
  double* ACC1 = ACC;
  double* ACC2 = ACC + 20;
  // H2 aliases PBDI (dead after k_tail1)
  float*  H2 = (float*)PBDI;

  hipMemsetAsync(ACC, 0, 40 * sizeof(double), stream);
  k_knn<<<(NPTS / 256) * SPLIT, 256, 0, stream>>>(x, PBDI);
  k_tail1<<<NPTS / 64, 256, 0, stream>>>(x, PBDI, W1, b1, H1, ACC1);
  k_mlp2<<<NROWS / 256, 256, 0, stream>>>(H1, ACC1, g1, be1, W2, b2, H2, ACC2);
  k_out<<<NPTS / 256, 256, 0, stream>>>(H2, ACC2, g2, be2, out);
}

// Round 14
// 258.226 us; speedup vs baseline: 1.3893x; 1.0646x over previous
//
#include <hip/hip_runtime.h>
#include <math.h>
#include <float.h>
#include <stdint.h>

#define B_ 4
#define N_ 8192
#define K_ 9
#define NPTS (B_ * N_)           // 32768
#define NROWS (NPTS * K_)        // 294912
#define SPLIT 8
#define CHUNK (N_ / SPLIT)       // 1024
#define NGROUP 32
#define GSIZE (CHUNK / NGROUP)   // 32
#define GSTRIDE 33               // +1 float4 pad

// Distance: EXACT source shape of all passing rounds. Plain mul/add tree —
// identical expression tree in every kernel -> bit-identical distances
// everywhere. DO NOT rewrite with explicit fmaf / reassociation (round 5
// flipped a knife-edge 9th/10th-neighbor decision vs the reference).
__device__ __forceinline__ float dist2f(float4 q, float4 c) {
  float dot = q.x * c.x + q.y * c.y + q.z * c.z;
  return (q.w + c.w) - 2.0f * dot;
}

// ---------------- K1: two-level exact top-9 per 1024-chunk, LDS-staged ----------
// 128-thread blocks: grid = 2048 = 8 blocks/CU at (128,4) (16 waves/CU, 128-reg
// budget). All per-lane state in NAMED SCALARS (arrays -> scratch).
#define GDECL(G) float gd##G; int gi##G;
#define SCANG(G)                                                           \
  { float bgd = FLT_MAX; int bgi = 0;                                      \
    _Pragma("clang loop unroll(disable)")                                  \
    for (int jj = 0; jj < GSIZE; jj += 4) {                                \
      const float4* cp = CH + (G * GSTRIDE + jj);                          \
      float4 c0 = cp[0], c1 = cp[1], c2 = cp[2], c3 = cp[3];               \
      int j = G * GSIZE + jj;                                              \
      float d0 = dist2f(q, c0), d1 = dist2f(q, c1);                        \
      float d2 = dist2f(q, c2), d3 = dist2f(q, c3);                        \
      if (HS) {                                                            \
        d0 = (j + 0 == nl) ? FLT_MAX : d0;                                 \
        d1 = (j + 1 == nl) ? FLT_MAX : d1;                                 \
        d2 = (j + 2 == nl) ? FLT_MAX : d2;                                 \
        d3 = (j + 3 == nl) ? FLT_MAX : d3;                                 \
      }                                                                    \
      bool l0 = d0 < bgd; bgd = l0 ? d0 : bgd; bgi = l0 ? (j + 0) : bgi;   \
      bool l1 = d1 < bgd; bgd = l1 ? d1 : bgd; bgi = l1 ? (j + 1) : bgi;   \
      bool l2 = d2 < bgd; bgd = l2 ? d2 : bgd; bgi = l2 ? (j + 2) : bgi;   \
      bool l3 = d3 < bgd; bgd = l3 ? d3 : bgd; bgi = l3 ? (j + 3) : bgi;   \
    }                                                                      \
    gd##G = bgd; gi##G = bgi; }
// Group lex-min WITHOUT index compare: groups partition ascending index
// ranges, so strict-< in ascending group order == exact (d, index) order.
#define LM(G)                                                              \
  { bool lt = gd##G < wd;                                                  \
    wd = lt ? gd##G : wd; wi = lt ? gi##G : wi; wg = lt ? G : wg; }
#define WBK(G)                                                             \
  { bool m = (wg == G); gd##G = m ? nd : gd##G; gi##G = m ? ni : gi##G; }

template <bool HS>
__device__ __forceinline__ void knn_chunk(const float4* CH, float4 q, int nl,
                                          int j0, int s, int p,
                                          uint2* __restrict__ PBDI) {
  GDECL(0) GDECL(1) GDECL(2) GDECL(3) GDECL(4) GDECL(5) GDECL(6) GDECL(7)
  GDECL(8) GDECL(9) GDECL(10) GDECL(11) GDECL(12) GDECL(13) GDECL(14) GDECL(15)
  GDECL(16) GDECL(17) GDECL(18) GDECL(19) GDECL(20) GDECL(21) GDECL(22) GDECL(23)
  GDECL(24) GDECL(25) GDECL(26) GDECL(27) GDECL(28) GDECL(29) GDECL(30) GDECL(31)

  SCANG(0) SCANG(1) SCANG(2) SCANG(3) SCANG(4) SCANG(5) SCANG(6) SCANG(7)
  SCANG(8) SCANG(9) SCANG(10) SCANG(11) SCANG(12) SCANG(13) SCANG(14) SCANG(15)
  SCANG(16) SCANG(17) SCANG(18) SCANG(19) SCANG(20) SCANG(21) SCANG(22) SCANG(23)
  SCANG(24) SCANG(25) SCANG(26) SCANG(27) SCANG(28) SCANG(29) SCANG(30) SCANG(31)

#pragma clang loop unroll(disable)
  for (int r = 0; r < K_; ++r) {
    float wd = gd0; int wi = gi0; int wg = 0;
    LM(1) LM(2) LM(3) LM(4) LM(5) LM(6) LM(7)
    LM(8) LM(9) LM(10) LM(11) LM(12) LM(13) LM(14) LM(15)
    LM(16) LM(17) LM(18) LM(19) LM(20) LM(21) LM(22) LM(23)
    LM(24) LM(25) LM(26) LM(27) LM(28) LM(29) LM(30) LM(31)
    uint2 o; o.x = __float_as_uint(wd); o.y = (unsigned)(j0 + wi);
    PBDI[(size_t)(s * K_ + r) * NPTS + p] = o;     // coalesced 8B

    // refill winning group: lex-min over keys strictly > (wd, wi) [local idx].
    // The FULL lex compare is REQUIRED: all candidates extracted from this
    // group in earlier rounds have keys lex-<= (wd, wi), and this one
    // comparison excludes the whole extraction history. Round 13 replaced it
    // with `j == wi` (excludes only the latest) -> duplicated neighbors when
    // a group wins multiple rounds. DO NOT weaken this test.
    int ab = wg * GSTRIDE;
    int jb = wg * GSIZE;
    float nd = FLT_MAX; int ni = 0;
#pragma clang loop unroll(disable)
    for (int jj = 0; jj < GSIZE; jj += 4) {
      const float4* cp = CH + (ab + jj);
      float4 c0 = cp[0], c1 = cp[1], c2 = cp[2], c3 = cp[3];
      int j = jb + jj;
      float d0 = dist2f(q, c0), d1 = dist2f(q, c1);
      float d2 = dist2f(q, c2), d3 = dist2f(q, c3);
      if (HS) {
        d0 = (j + 0 == nl) ? FLT_MAX : d0;
        d1 = (j + 1 == nl) ? FLT_MAX : d1;
        d2 = (j + 2 == nl) ? FLT_MAX : d2;
        d3 = (j + 3 == nl) ? FLT_MAX : d3;
      }
      bool k0 = (d0 > wd) | ((d0 == wd) & ((j + 0) > wi));
      bool k1 = (d1 > wd) | ((d1 == wd) & ((j + 1) > wi));
      bool k2 = (d2 > wd) | ((d2 == wd) & ((j + 2) > wi));
      bool k3 = (d3 > wd) | ((d3 == wd) & ((j + 3) > wi));
      d0 = k0 ? d0 : FLT_MAX;
      d1 = k1 ? d1 : FLT_MAX;
      d2 = k2 ? d2 : FLT_MAX;
      d3 = k3 ? d3 : FLT_MAX;
      bool l0 = d0 < nd; nd = l0 ? d0 : nd; ni = l0 ? (j + 0) : ni;
      bool l1 = d1 < nd; nd = l1 ? d1 : nd; ni = l1 ? (j + 1) : ni;
      bool l2 = d2 < nd; nd = l2 ? d2 : nd; ni = l2 ? (j + 2) : ni;
      bool l3 = d3 < nd; nd = l3 ? d3 : nd; ni = l3 ? (j + 3) : ni;
    }
    WBK(0) WBK(1) WBK(2) WBK(3) WBK(4) WBK(5) WBK(6) WBK(7)
    WBK(8) WBK(9) WBK(10) WBK(11) WBK(12) WBK(13) WBK(14) WBK(15)
    WBK(16) WBK(17) WBK(18) WBK(19) WBK(20) WBK(21) WBK(22) WBK(23)
    WBK(24) WBK(25) WBK(26) WBK(27) WBK(28) WBK(29) WBK(30) WBK(31)
  }
}

__launch_bounds__(128, 4)
__global__ void k_knn(const float* __restrict__ x, uint2* __restrict__ PBDI) {
  __shared__ float4 CH[NGROUP * GSTRIDE];   // 16896 B; 8 blocks/CU = 135 KB
  int bid = blockIdx.x;
  int pg = bid >> 3;                 // 128-point range [0,256)
  int s = bid & (SPLIT - 1);
  int p = pg * 128 + threadIdx.x;
  int b = p >> 13;                   // block-uniform (128-aligned range)
  int n = p & (N_ - 1);
  int bO = b * N_;
  int j0 = s * CHUNK;

  const float* xq = x + 3 * (size_t)p;
  float qa = xq[0], qb = xq[1], qc = xq[2];
  float4 q = make_float4(qa, qb, qc, qa * qa + qb * qb + qc * qc);

  // stage chunk -> LDS from x; w = a*a+b*b+c*c (EXACT expression everywhere)
  for (int t = threadIdx.x; t < CHUNK; t += 128) {
    const float* xp = x + 3 * (size_t)(bO + j0 + t);
    float a = xp[0], bb = xp[1], cc = xp[2];
    CH[(t >> 5) * GSTRIDE + (t & 31)] = make_float4(a, bb, cc, a * a + bb * bb + cc * cc);
  }
  __syncthreads();

  int n0 = (pg * 128) & (N_ - 1);    // block-uniform
  int nl = n - j0;                   // local self index (valid only if HS)
  if (s == (n0 >> 10)) knn_chunk<true >(CH, q, nl, j0, s, p, PBDI);
  else                 knn_chunk<false>(CH, q, nl, j0, s, p, PBDI);
}

// ---------------- K2: merge + phi-sort + features + W1 -> H1 + stats1 ----------
// 512 blocks x 256 threads = 4 threads/point. Wave q sub-merges lists
// s in [2q, 2q+2) (ascending (s,rank) -> exact tie-breaking); wave 0 does the
// final 4-way merge (ascending q = ascending s) + sort; rows fan out to all
// 256 threads. No grid barriers — launch boundaries provide global sync
// (round 11's 512-block spin barriers regressed ~70 µs).
#define LVL(bdv, biv)                                                     \
  { bool lt = cd < (bdv); float td = (bdv); int ti = (biv);               \
    (bdv) = lt ? cd : (bdv); (biv) = lt ? ci : (biv);                     \
    cd = lt ? td : cd; ci = lt ? ti : ci; }
#define INS9ALL()                                                         \
  LVL(b0d, b0i) LVL(b1d, b1i) LVL(b2d, b2i) LVL(b3d, b3i) LVL(b4d, b4i)  \
  LVL(b5d, b5i) LVL(b6d, b6i) LVL(b7d, b7i) LVL(b8d, b8i)
#define TOP9_DECL()                                                       \
  float b0d = FLT_MAX, b1d = FLT_MAX, b2d = FLT_MAX, b3d = FLT_MAX,       \
        b4d = FLT_MAX, b5d = FLT_MAX, b6d = FLT_MAX, b7d = FLT_MAX,       \
        b8d = FLT_MAX;                                                    \
  int b0i = 0, b1i = 0, b2i = 0, b3i = 0, b4i = 0, b5i = 0, b6i = 0,      \
      b7i = 0, b8i = 0;

#define MKREL(T)                                                          \
  float rx##T, ry##T, rz##T, ph##T;                                       \
  { const float* mp = x + 3 * (size_t)(bO + b##T##i);                     \
    rx##T = mp[0] - qa; ry##T = mp[1] - qb; rz##T = mp[2] - qc;           \
    ph##T = atan2f(ry##T, rx##T); }

#define CE(A, Bv)                                                         \
  { bool lt = ph##Bv < ph##A; float t0;                                   \
    t0 = ph##A; ph##A = lt ? ph##Bv : t0; ph##Bv = lt ? t0 : ph##Bv;      \
    t0 = rx##A; rx##A = lt ? rx##Bv : t0; rx##Bv = lt ? t0 : rx##Bv;      \
    t0 = ry##A; ry##A = lt ? ry##Bv : t0; ry##Bv = lt ? t0 : ry##Bv;      \
    t0 = rz##A; rz##A = lt ? rz##Bv : t0; rz##Bv = lt ? t0 : rz##Bv; }

#define ST9(arr, v0, v1, v2, v3, v4, v5, v6, v7, v8)                      \
  arr[0 * 64 + pl] = v0; arr[1 * 64 + pl] = v1; arr[2 * 64 + pl] = v2;    \
  arr[3 * 64 + pl] = v3; arr[4 * 64 + pl] = v4; arr[5 * 64 + pl] = v5;    \
  arr[6 * 64 + pl] = v6; arr[7 * 64 + pl] = v7; arr[8 * 64 + pl] = v8;

__launch_bounds__(256, 4)
__global__ void k_tail1(const float* __restrict__ x, const uint2* __restrict__ PBDI,
                        const float* __restrict__ W1, const float* __restrict__ b1,
                        float* __restrict__ H1, double* __restrict__ ACC1) {
  __shared__ float  LMD[64 * 37];        // [pl*37 + q*9 + r], odd stride
  __shared__ int    LMI[64 * 37];
  __shared__ float  LREL[3][9 * 64];     // [comp][t*64 + pl]
  __shared__ float  LSGN[64];
  __shared__ double sred[4][20];

  int q = threadIdx.x >> 6;              // wave id 0..3
  int pl = threadIdx.x & 63;
  int pbase = blockIdx.x * 64;
  int p = pbase + pl;

  // ---- sub-merge: wave q merges lists s in [2q, 2q+2) (18 coalesced entries)
  {
    TOP9_DECL();
#pragma clang loop unroll_count(2)
    for (int e = 0; e < 2 * K_; ++e) {
      uint2 v = PBDI[(size_t)(q * 2 * K_ + e) * NPTS + p];
      float cd = __uint_as_float(v.x);
      int ci = (int)v.y;
      INS9ALL();
    }
    int base = pl * 37 + q * 9;
    LMD[base + 0] = b0d; LMD[base + 1] = b1d; LMD[base + 2] = b2d;
    LMD[base + 3] = b3d; LMD[base + 4] = b4d; LMD[base + 5] = b5d;
    LMD[base + 6] = b6d; LMD[base + 7] = b7d; LMD[base + 8] = b8d;
    LMI[base + 0] = b0i; LMI[base + 1] = b1i; LMI[base + 2] = b2i;
    LMI[base + 3] = b3i; LMI[base + 4] = b4i; LMI[base + 5] = b5i;
    LMI[base + 6] = b6i; LMI[base + 7] = b7i; LMI[base + 8] = b8i;
  }
  __syncthreads();

  // ---- final merge + REL + phi-sort + sign (wave 0, one lane per point) ----
  if (q == 0) {
    int b = p >> 13;
    int bO = b * N_;
    const float* xq = x + 3 * (size_t)p;
    float qa = xq[0], qb = xq[1], qc = xq[2];

    TOP9_DECL();
#pragma clang loop unroll_count(3)
    for (int e = 0; e < 4 * K_; ++e) {   // ascending q (=s) then rank
      float cd = LMD[pl * 37 + e];
      int ci = LMI[pl * 37 + e];
      INS9ALL();
    }

    MKREL(0) MKREL(1) MKREL(2) MKREL(3) MKREL(4)
    MKREL(5) MKREL(6) MKREL(7) MKREL(8)

    // stable insertion-sort network ascending by phi (36 strict-< CEs)
    CE(0,1)
    CE(1,2) CE(0,1)
    CE(2,3) CE(1,2) CE(0,1)
    CE(3,4) CE(2,3) CE(1,2) CE(0,1)
    CE(4,5) CE(3,4) CE(2,3) CE(1,2) CE(0,1)
    CE(5,6) CE(4,5) CE(3,4) CE(2,3) CE(1,2) CE(0,1)
    CE(6,7) CE(5,6) CE(4,5) CE(3,4) CE(2,3) CE(1,2) CE(0,1)
    CE(7,8) CE(6,7) CE(5,6) CE(4,5) CE(3,4) CE(2,3) CE(1,2) CE(0,1)

    // sign from triangle 0's NORMALIZED nx (reference semantics)
    float nx0 = ry0 * rz1 - rz0 * ry1;
    float ny0 = rz0 * rx1 - rx0 * rz1;
    float nz0 = rx0 * ry1 - ry0 * rx1;
    float nrm0 = sqrtf(nx0 * nx0 + ny0 * ny0 + nz0 * nz0) + 1e-6f;
    LSGN[pl] = ((nx0 / nrm0) > 0.0f) ? 1.0f : -1.0f;

    ST9(LREL[0], rx0, rx1, rx2, rx3, rx4, rx5, rx6, rx7, rx8)
    ST9(LREL[1], ry0, ry1, ry2, ry3, ry4, ry5, ry6, ry7, ry8)
    ST9(LREL[2], rz0, rz1, rz2, rz3, rz4, rz5, rz6, rz7, rz8)
  }
  __syncthreads();

  // ---- rows: 576 rows / 256 threads; feat + W1 -> H1 + fp64 stats ----
  double sum[10], ss[10];
#pragma unroll
  for (int c = 0; c < 10; ++c) { sum[c] = 0.0; ss[c] = 0.0; }

#pragma clang loop unroll(disable)
  for (int rl = threadIdx.x; rl < 9 * 64; rl += 256) {
    int t = rl >> 6;
    int pp = rl & 63;
    int t2 = (t + 1 == K_) ? 0 : t + 1;
    float v1x = LREL[0][t * 64 + pp];
    float v1y = LREL[1][t * 64 + pp];
    float v1z = LREL[2][t * 64 + pp];
    float v2x = LREL[0][t2 * 64 + pp];
    float v2y = LREL[1][t2 * 64 + pp];
    float v2z = LREL[2][t2 * 64 + pp];
    float sgn = LSGN[pp];

    float cx = 0.5f * (v1x + v2x);
    float cy = 0.5f * (v1y + v2y);
    float cz = 0.5f * (v1z + v2z);
    float nx = v1y * v2z - v1z * v2y;
    float ny = v1z * v2x - v1x * v2z;
    float nz = v1x * v2y - v1y * v2x;
    float nrm = sqrtf(nx * nx + ny * ny + nz * nz) + 1e-6f;
    nx /= nrm; ny /= nrm; nz /= nrm;
    nx *= sgn; ny *= sgn; nz *= sgn;
    float pos = (nx * cx + ny * cy + nz * cz) / 1.7320508075688772f;

    float fv[7] = {cx, cy, cz, nx, ny, nz, pos};
#pragma unroll
    for (int c = 0; c < 10; ++c) {
      float h = b1[c];
#pragma unroll
      for (int rr = 0; rr < 7; ++rr) h = fmaf(fv[rr], W1[rr * 10 + c], h);
      H1[(size_t)c * NROWS + (size_t)t * NPTS + pbase + pp] = h;  // coalesced
      double hd = (double)h;
      sum[c] += hd; ss[c] += hd * hd;
    }
  }

  int lane = threadIdx.x & 63, wv = threadIdx.x >> 6;
#pragma unroll
  for (int c = 0; c < 10; ++c) {
    double a = sum[c];
#pragma unroll
    for (int off = 32; off > 0; off >>= 1) a += __shfl_down(a, off);
    if (lane == 0) sred[wv][c] = a;
    double qq = ss[c];
#pragma unroll
    for (int off = 32; off > 0; off >>= 1) qq += __shfl_down(qq, off);
    if (lane == 0) sred[wv][10 + c] = qq;
  }
  __syncthreads();
  if (threadIdx.x < 20) {
    atomicAdd(&ACC1[threadIdx.x],
              sred[0][threadIdx.x] + sred[1][threadIdx.x] +
              sred[2][threadIdx.x] + sred[3][threadIdx.x]);
  }
}

// ---------------- K3: bn1(from ACC1) + relu + @W2+b2 -> H2 + stats2 ------------
__launch_bounds__(256)
__global__ void k_mlp2(const float* __restrict__ H1, const double* __restrict__ ACC1,
                       const float* __restrict__ g1, const float* __restrict__ be1,
                       const float* __restrict__ W2, const float* __restrict__ b2,
                       float* __restrict__ H2, double* __restrict__ ACC2) {
  __shared__ float MR[20];
  if (threadIdx.x < 10) {
    double mu = ACC1[threadIdx.x] / (double)NROWS;
    double var = ACC1[10 + threadIdx.x] / (double)NROWS - mu * mu;
    MR[threadIdx.x] = (float)mu;
    MR[10 + threadIdx.x] = (float)(1.0 / sqrt(var + 1e-5));
  }
  __syncthreads();

  int r = blockIdx.x * 256 + threadIdx.x;
  float v[10];
#pragma unroll
  for (int c = 0; c < 10; ++c) {
    float h = H1[(size_t)c * NROWS + r];
    float z = g1[c] * (h - MR[c]) * MR[10 + c] + be1[c];
    v[c] = z > 0.0f ? z : 0.0f;
  }
  float o[10];
#pragma unroll
  for (int c = 0; c < 10; ++c) {
    float h = b2[c];
#pragma unroll
    for (int t = 0; t < 10; ++t) h = fmaf(v[t], W2[t * 10 + c], h);
    o[c] = h;
    H2[(size_t)c * NROWS + r] = h;
  }

  __shared__ double sred[4][20];
  int lane = threadIdx.x & 63, wv = threadIdx.x >> 6;
#pragma unroll
  for (int c = 0; c < 10; ++c) {
    double a = (double)o[c];
#pragma unroll
    for (int off = 32; off > 0; off >>= 1) a += __shfl_down(a, off);
    if (lane == 0) sred[wv][c] = a;
    double qq = (double)o[c] * (double)o[c];
#pragma unroll
    for (int off = 32; off > 0; off >>= 1) qq += __shfl_down(qq, off);
    if (lane == 0) sred[wv][10 + c] = qq;
  }
  __syncthreads();
  if (threadIdx.x < 20) {
    atomicAdd(&ACC2[threadIdx.x],
              sred[0][threadIdx.x] + sred[1][threadIdx.x] +
              sred[2][threadIdx.x] + sred[3][threadIdx.x]);
  }
}

// ---------------- K4: bn2(from ACC2) + relu + max over k -> out -----------------
__launch_bounds__(256)
__global__ void k_out(const float* __restrict__ H2, const double* __restrict__ ACC2,
                      const float* __restrict__ g2, const float* __restrict__ be2,
                      float* __restrict__ out) {
  __shared__ float MR[20];
  if (threadIdx.x < 10) {
    double mu = ACC2[threadIdx.x] / (double)NROWS;
    double var = ACC2[10 + threadIdx.x] / (double)NROWS - mu * mu;
    MR[threadIdx.x] = (float)mu;
    MR[10 + threadIdx.x] = (float)(1.0 / sqrt(var + 1e-5));
  }
  __syncthreads();

  int p = blockIdx.x * 256 + threadIdx.x;
#pragma unroll
  for (int c = 0; c < 10; ++c) {
    float m = -FLT_MAX;
#pragma unroll
    for (int j = 0; j < K_; ++j) {
      float h = H2[(size_t)c * NROWS + j * NPTS + p];   // coalesced
      float z = g2[c] * (h - MR[c]) * MR[10 + c] + be2[c];
      z = z > 0.0f ? z : 0.0f;
      m = fmaxf(m, z);
    }
    out[(size_t)p * 10 + c] = m;
  }
}

extern "C" void kernel_launch(void* const* d_in, const int* in_sizes, int n_in,
                              void* d_out, int out_size, void* d_ws, size_t ws_size,
                              hipStream_t stream) {
  (void)in_sizes; (void)n_in; (void)out_size; (void)ws_size;
  const float* x  = (const float*)d_in[0];
  const float* W1 = (const float*)d_in[1];
  const float* b1 = (const float*)d_in[2];
  const float* g1 = (const float*)d_in[3];
  const float* be1= (const float*)d_in[4];
  const float* W2 = (const float*)d_in[5];
  const float* b2 = (const float*)d_in[6];
  const float* g2 = (const float*)d_in[7];
  const float* be2= (const float*)d_in[8];
  float* out = (float*)d_out;

  char* base = (char*)d_ws;
  uint2*  PBDI = (uint2*)base;                          // 72 slices, 18.9 MB
  float*  H1 = (float*)(base + (size_t)SPLIT * K_ * NPTS * 8);  // 11.8 MB
  double* ACC = (double*)(H1 + (size_t)10 * NROWS);     // 40 doubles
  double* ACC1 = ACC;
  double* ACC2 = ACC + 20;
  // H2 aliases PBDI (dead after k_tail1)
  float*  H2 = (float*)PBDI;                            // 11.8 of 18.9 MB

  hipMemsetAsync(ACC, 0, 40 * sizeof(double), stream);
  k_knn<<<(NPTS / 128) * SPLIT, 128, 0, stream>>>(x, PBDI);
  k_tail1<<<NPTS / 64, 256, 0, stream>>>(x, PBDI, W1, b1, H1, ACC1);
  k_mlp2<<<NROWS / 256, 256, 0, stream>>>(H1, ACC1, g1, be1, W2, b2, H2, ACC2);
  k_out<<<NPTS / 256, 256, 0, stream>>>(H2, ACC2, g2, be2, out);
}